// Round 17
// baseline (133.806 us; speedup 1.0000x reference)
//
#include <hip/hip_runtime.h>

#define B_   32
#define D_   256
#define HW_  1024
#define N_   32768
#define K_   1024
#define DHW  (D_ * HW_)      // 262144
#define MARGIN 0.3f

typedef __attribute__((ext_vector_type(8)))  short bf16x8;
typedef __attribute__((ext_vector_type(16))) float f32x16;

union FragU { uint4 q; bf16x8 v; };

#define MFMA32 __builtin_amdgcn_mfma_f32_32x32x16_bf16

__device__ inline uint bf16rne(float x) {
    uint ub = __float_as_uint(x);
    return (ub + 0x7fffu + ((ub >> 16) & 1u)) >> 16;
}

// ================= prep_cb: codebook -> d-outer hi/lo planes + csq + cbT; zero-init ====
__global__ __launch_bounds__(256)
void prep_cb(const float* __restrict__ cb, uint4* __restrict__ cbt2,
             float* __restrict__ csq, float* __restrict__ cbT,
             int* __restrict__ rcount, float* __restrict__ oloss) {
    __shared__ uint sh[256], sl[256];
    __shared__ float rr[4];
    const int k = blockIdx.x, d = threadIdx.x;
    float v = cb[(size_t)k * D_ + d];
    uint hb = bf16rne(v);
    float hf = __uint_as_float(hb << 16);
    uint lb = bf16rne(v - hf);
    sh[d] = hb; sl[d] = lb;
    cbT[(size_t)d * K_ + k] = v;
    float s = v * v;
    #pragma unroll
    for (int off = 32; off >= 1; off >>= 1) s += __shfl_xor(s, off, 64);
    if ((d & 63) == 0) rr[d >> 6] = s;
    __syncthreads();
    if (d == 0) csq[k] = (rr[0] + rr[1]) + (rr[2] + rr[3]);
    if (k == 0 && d == 0) { *rcount = 0; oloss[0] = 0.f; oloss[1] = 0.f; }
    if (d < 64) {
        const int ch = d >> 2, it = d & 3;
        const int p = it >> 1, h = it & 1;
        const int d0 = ch * 16 + h * 8;
        const uint* src = p ? sl : sh;
        uint w[4];
        #pragma unroll
        for (int jj = 0; jj < 4; ++jj)
            w[jj] = src[d0 + 2 * jj] | (src[d0 + 2 * jj + 1] << 16);
        cbt2[((ch * 4 + it) << 10) + k] = make_uint4(w[0], w[1], w[2], w[3]);
    }
}

// ================= main: 16-wave TLP K-loop (4 waves/SIMD), fused gather ==========
// 256 blocks x 1024 thr. Block: 128 tokens x 1024 codes.
// Wave w: th = w&1 (token half, 64 tokens), cs = w>>1 (code slice);
// 2 phases: codes cs*64 + p*512. acc = 2x2 f32x16 = 64 AGPR.
__global__ __launch_bounds__(1024, 4)
void vq_main(const float* __restrict__ x, const uint4* __restrict__ cbt2,
             const float* __restrict__ csqg, const float* __restrict__ cb,
             int* __restrict__ rcount, int* __restrict__ rlist,
             float* __restrict__ bdist, float* __restrict__ out,
             float* __restrict__ oidx, float* __restrict__ oloss) {
    __shared__ __align__(16) uint SMEM[17408];   // 68 KB
    uint4 (*TkS)[128] = reinterpret_cast<uint4(*)[128]>(SMEM);   // [32][128] 64 KB
    float* csqS = reinterpret_cast<float*>(SMEM + 16384);        // 4 KB

    const int tid = threadIdx.x;
    const int lane = tid & 63;
    const int sub = lane >> 5, l31 = lane & 31;
    const int w = tid >> 6;            // 0..15
    const int th = w & 1;              // token half
    const int cs = w >> 1;             // code slice 0..7
    const int tok0 = blockIdx.x * 128;
    const int bb = tok0 >> 10, hw0 = tok0 & 1023;

    csqS[tid] = csqg[tid];

    // ---- fused x -> bf16 staging into TkS[g][t] ----
    {
        const int t = tid & 127;
        const int dgrp = tid >> 7;     // 0..7 (wave-uniform)
        const float* xp = x + (size_t)bb * DHW + hw0 + t;
        #pragma unroll
        for (int i = 0; i < 4; ++i) {
            int g = i * 8 + dgrp;      // 0..31, d = 8g..8g+7
            float v[8];
            #pragma unroll
            for (int e = 0; e < 8; ++e)
                v[e] = xp[(size_t)(g * 8 + e) * HW_];
            uint wd[4];
            #pragma unroll
            for (int jj = 0; jj < 4; ++jj)
                wd[jj] = bf16rne(v[2 * jj]) | (bf16rne(v[2 * jj + 1]) << 16);
            TkS[g][t] = make_uint4(wd[0], wd[1], wd[2], wd[3]);
        }
    }
    __syncthreads();

    f32x16 acc[2][2] = {};
    float v1[2] = {3.4e38f, 3.4e38f}, v2[2] = {3.4e38f, 3.4e38f};
    int k1[2] = {0, 0};

    const uint4* cbh = cbt2 + (sub << 10) + cs * 64 + l31;          // hi plane base
    const uint4* cbl = cbt2 + ((2 + sub) << 10) + cs * 64 + l31;    // lo plane base

    #pragma unroll
    for (int s = 0; s < 32; ++s) {
        const int p = s >> 4, ch = s & 15;
        const int off = ((ch * 4) << 10) + p * 512;
        FragU ah0, ah1, al0, al1, tf0, tf1;
        ah0.q = cbh[off];        ah1.q = cbh[off + 32];
        al0.q = cbl[off];        al1.q = cbl[off + 32];
        tf0.q = TkS[ch * 2 + sub][th * 64 + l31];
        tf1.q = TkS[ch * 2 + sub][th * 64 + 32 + l31];

        __builtin_amdgcn_s_setprio(1);
        acc[0][0] = MFMA32(ah0.v, tf0.v, acc[0][0], 0, 0, 0);
        acc[0][1] = MFMA32(ah0.v, tf1.v, acc[0][1], 0, 0, 0);
        acc[1][0] = MFMA32(ah1.v, tf0.v, acc[1][0], 0, 0, 0);
        acc[1][1] = MFMA32(ah1.v, tf1.v, acc[1][1], 0, 0, 0);
        acc[0][0] = MFMA32(al0.v, tf0.v, acc[0][0], 0, 0, 0);
        acc[0][1] = MFMA32(al0.v, tf1.v, acc[0][1], 0, 0, 0);
        acc[1][0] = MFMA32(al1.v, tf0.v, acc[1][0], 0, 0, 0);
        acc[1][1] = MFMA32(al1.v, tf1.v, acc[1][1], 0, 0, 0);
        __builtin_amdgcn_s_setprio(0);

        // ---- per-phase epilogue after full 256-d sweep ----
        if (ch == 15) {
            const int cgbase = p * 512 + cs * 64 + sub * 4;
            #pragma unroll
            for (int f = 0; f < 2; ++f) {
                #pragma unroll
                for (int g8 = 0; g8 < 4; ++g8) {
                    float4 cs4 = *reinterpret_cast<const float4*>(&csqS[cgbase + f * 32 + g8 * 8]);
                    const float csa[4] = {cs4.x, cs4.y, cs4.z, cs4.w};
                    #pragma unroll
                    for (int q = 0; q < 4; ++q) {
                        int code = cgbase + f * 32 + g8 * 8 + q;
                        int r = g8 * 4 + q;
                        #pragma unroll
                        for (int j = 0; j < 2; ++j) {
                            float sd = fmaf(-2.f, acc[f][j][r], csa[q]);
                            bool c = sd < v1[j];
                            v2[j] = c ? v1[j] : fminf(v2[j], sd);
                            k1[j] = c ? code : k1[j];
                            v1[j] = c ? sd : v1[j];
                        }
                    }
                }
            }
            const f32x16 zf = {};
            #pragma unroll
            for (int f = 0; f < 2; ++f)
                #pragma unroll
                for (int j = 0; j < 2; ++j) acc[f][j] = zf;
        }
    }

    // ---- merge sub halves (codes interleaved across sub) ----
    #pragma unroll
    for (int j = 0; j < 2; ++j) {
        float ov1 = __shfl_xor(v1[j], 32, 64);
        float ov2 = __shfl_xor(v2[j], 32, 64);
        int   ok1 = __shfl_xor(k1[j], 32, 64);
        float nv2 = fminf(fminf(v2[j], ov2), fmaxf(v1[j], ov1));
        if (ov1 < v1[j] || (ov1 == v1[j] && ok1 < k1[j])) { v1[j] = ov1; k1[j] = ok1; }
        v2[j] = nv2;
    }
    __syncthreads();
    float* red = reinterpret_cast<float*>(SMEM);            // [8 cs][128 t][3]
    int* bestk_s = reinterpret_cast<int*>(SMEM + 17280);    // 128 ints (tail, survives S2)
    if (sub == 0) {
        #pragma unroll
        for (int j = 0; j < 2; ++j) {
            int t = th * 64 + j * 32 + l31;
            red[(cs * 128 + t) * 3 + 0] = v1[j];
            red[(cs * 128 + t) * 3 + 1] = v2[j];
            red[(cs * 128 + t) * 3 + 2] = __int_as_float(k1[j]);
        }
    }
    __syncthreads();
    if (tid < 128) {
        float bv1 = red[tid * 3], bv2 = red[tid * 3 + 1];
        int bk = __float_as_int(red[tid * 3 + 2]);
        #pragma unroll
        for (int m = 1; m < 8; ++m) {
            float a1 = red[(m * 128 + tid) * 3], a2 = red[(m * 128 + tid) * 3 + 1];
            int ak = __float_as_int(red[(m * 128 + tid) * 3 + 2]);
            float nv2 = fminf(fminf(bv2, a2), fmaxf(bv1, a1));
            if (a1 < bv1 || (a1 == bv1 && ak < bk)) { bv1 = a1; bk = ak; }
            bv2 = nv2;
        }
        int n = tok0 + tid;
        bestk_s[tid] = bk;
        bdist[n] = bv1;
        oidx[n] = (float)bk;
        if (bv2 - bv1 < MARGIN) rlist[atomicAdd(rcount, 1)] = n;
        float v = bv1;
        #pragma unroll
        for (int off = 32; off >= 1; off >>= 1) v += __shfl_xor(v, off, 64);
        if ((tid & 63) == 0) {
            float t2 = v * (1.0f / 8388608.0f);
            atomicAdd(&oloss[0], t2);
            atomicAdd(&oloss[1], t2);
        }
    }
    __syncthreads();

    // ---- gather via LDS transpose: 2 halves of 64 tokens ----
    float* S2 = reinterpret_cast<float*>(SMEM);   // [64][260] = 66,560 B
    #pragma unroll 1
    for (int h = 0; h < 2; ++h) {
        // fill: wave w loads rows w*4..w*4+4 coalesced (1 dwordx4 per row)
        #pragma unroll
        for (int i = 0; i < 4; ++i) {
            int r = w * 4 + i;                       // 0..63
            int kk = bestk_s[h * 64 + r];
            float4 cw4 = *reinterpret_cast<const float4*>(cb + (size_t)kk * D_ + lane * 4);
            *reinterpret_cast<float4*>(&S2[r * 260 + lane * 4]) = cw4;
        }
        __syncthreads();
        // store: q = token-quad (tid&15), dg = d-group (tid>>4, 0..63)
        {
            const int q = tid & 15, dg = tid >> 4;
            const size_t obase = (size_t)bb * DHW + hw0 + h * 64 + q * 4;
            #pragma unroll
            for (int dd = 0; dd < 4; ++dd) {
                int d = dg * 4 + dd;
                float4 wv;
                wv.x = S2[(q * 4 + 0) * 260 + d];
                wv.y = S2[(q * 4 + 1) * 260 + d];
                wv.z = S2[(q * 4 + 2) * 260 + d];
                wv.w = S2[(q * 4 + 3) * 260 + d];
                *reinterpret_cast<float4*>(out + obase + (size_t)d * HW_) = wv;
            }
        }
        __syncthreads();
    }
}

// ===== exact fp32 refine: 256 thr, batch-8, 4 codes/thread + fix-up (r16, grid 512) =====
__global__ __launch_bounds__(256)
void vq_refine(const float* __restrict__ x, const float* __restrict__ cb,
               const float* __restrict__ cbT, const float* __restrict__ csq,
               const int* __restrict__ rcount, const int* __restrict__ rlist,
               const float* __restrict__ bdist, float* __restrict__ out,
               float* __restrict__ oidx, float* __restrict__ oloss) {
    __shared__ float xv[8][256];
    __shared__ float xsq[8];
    __shared__ float wredv[4][8];
    __shared__ int   wredk[4][8];
    __shared__ int   kfin[8];
    const int tid = threadIdx.x;
    const int cnt = min(rcount[0], N_);
    for (int base = blockIdx.x * 8; base < cnt; base += gridDim.x * 8) {
        const int m = min(8, cnt - base);
        __syncthreads();
        for (int j = 0; j < m; ++j) {
            int n = rlist[base + j];
            int b = n >> 10, hw = n & 1023;
            xv[j][tid] = x[(size_t)b * DHW + (size_t)tid * HW_ + hw];
        }
        for (int j = m; j < 8; ++j) xv[j][tid] = 0.f;
        __syncthreads();
        {   // xsq: 8 groups of 32 lanes (identical tree to prior passing rounds)
            int g = tid >> 5, l = tid & 31;
            float s = 0.f;
            #pragma unroll
            for (int d8 = 0; d8 < 8; ++d8) { float v = xv[g][d8 * 32 + l]; s = fmaf(v, v, s); }
            #pragma unroll
            for (int mm = 1; mm < 32; mm <<= 1) s += __shfl_xor(s, mm, 64);
            if (l == 0) xsq[g] = s;
        }
        __syncthreads();

        float dots[4][8];
        #pragma unroll
        for (int c4 = 0; c4 < 4; ++c4)
            #pragma unroll
            for (int j = 0; j < 8; ++j) dots[c4][j] = 0.f;

        const float* cbase = cbT + tid;
        for (int d0 = 0; d0 < 256; d0 += 8) {
            float xr[8][8];
            #pragma unroll
            for (int j = 0; j < 8; ++j) {
                float4 a = *reinterpret_cast<const float4*>(&xv[j][d0]);
                float4 b = *reinterpret_cast<const float4*>(&xv[j][d0 + 4]);
                xr[j][0] = a.x; xr[j][1] = a.y; xr[j][2] = a.z; xr[j][3] = a.w;
                xr[j][4] = b.x; xr[j][5] = b.y; xr[j][6] = b.z; xr[j][7] = b.w;
            }
            #pragma unroll
            for (int c4 = 0; c4 < 4; ++c4) {
                float cv[8];
                #pragma unroll
                for (int u = 0; u < 8; ++u)
                    cv[u] = cbase[(size_t)(d0 + u) * K_ + c4 * 256];   // coalesced
                #pragma unroll
                for (int u = 0; u < 8; ++u)
                    #pragma unroll
                    for (int j = 0; j < 8; ++j)
                        dots[c4][j] = fmaf(cv[u], xr[j][u], dots[c4][j]);
            }
        }

        float bv[8]; int bk[8];
        #pragma unroll
        for (int j = 0; j < 8; ++j) { bv[j] = 3.4e38f; bk[j] = 0; }
        #pragma unroll
        for (int c4 = 0; c4 < 4; ++c4) {
            const int code = c4 * 256 + tid;
            const float cs = csq[code];
            #pragma unroll
            for (int j = 0; j < 8; ++j) {
                float dist = fmaf(-2.f, dots[c4][j], xsq[j]) + cs;
                if (dist < bv[j]) { bv[j] = dist; bk[j] = code; }
            }
        }
        #pragma unroll
        for (int j = 0; j < 8; ++j) {
            if (j < m) {
                float v = bv[j]; int k = bk[j];
                #pragma unroll
                for (int mm = 1; mm < 64; mm <<= 1) {
                    float ov = __shfl_xor(v, mm, 64);
                    int   ok = __shfl_xor(k, mm, 64);
                    if (ov < v || (ov == v && ok < k)) { v = ov; k = ok; }
                }
                if ((tid & 63) == 0) { wredv[tid >> 6][j] = v; wredk[tid >> 6][j] = k; }
            }
        }
        __syncthreads();
        if (tid < m) {
            float v = wredv[0][tid]; int k = wredk[0][tid];
            #pragma unroll
            for (int q = 1; q < 4; ++q) {
                if (wredv[q][tid] < v || (wredv[q][tid] == v && wredk[q][tid] < k)) {
                    v = wredv[q][tid]; k = wredk[q][tid];
                }
            }
            int n = rlist[base + tid];
            kfin[tid] = k;
            oidx[n] = (float)k;
            float delta = (v - bdist[n]) * (1.0f / 8388608.0f);
            atomicAdd(&oloss[0], delta);
            atomicAdd(&oloss[1], delta);
        }
        __syncthreads();
        for (int j = 0; j < m; ++j) {
            int n = rlist[base + j];
            int b = n >> 10, hw = n & 1023;
            out[(size_t)b * DHW + (size_t)tid * HW_ + hw] = cb[(size_t)kfin[j] * D_ + tid];
        }
        __syncthreads();
    }
}

extern "C" void kernel_launch(void* const* d_in, const int* in_sizes, int n_in,
                              void* d_out, int out_size, void* d_ws, size_t ws_size,
                              hipStream_t stream) {
    const float* x  = (const float*)d_in[0];
    const float* cb = (const float*)d_in[1];

    float* out   = (float*)d_out;            // 8388608 floats
    float* oidx  = out + 8388608;            // 32768 floats
    float* oloss = out + 8388608 + 32768;    // 2 floats

    uint* wsb = (uint*)d_ws;
    uint4*  cbt2  = (uint4*)wsb;             // 1 MB
    float*  csq   = (float*)(wsb + 262144);  // 1024
    float*  cbT   = (float*)(wsb + 263168);  // 1 MB, fp32 [d][k]
    int*    rcount= (int*)  (wsb + 525312);  // 1
    int*    rlist = (int*)  (wsb + 525316);  // 32768
    float*  bdist = (float*)(wsb + 558084);  // 32768

    prep_cb <<<1024, 256, 0, stream>>>(cb, cbt2, csq, cbT, rcount, oloss);
    vq_main <<<256, 1024, 0, stream>>>(x, cbt2, csq, cb, rcount, rlist, bdist, out, oidx, oloss);
    vq_refine<<<512, 256, 0, stream>>>(x, cb, cbT, csq, rcount, rlist, bdist, out, oidx, oloss);
}

// Round 18
// 106.326 us; speedup vs baseline: 1.2585x; 1.2585x over previous
//
#include <hip/hip_runtime.h>

#define B_   32
#define D_   256
#define HW_  1024
#define N_   32768
#define K_   1024
#define DHW  (D_ * HW_)      // 262144
#define MARGIN 0.3f

typedef __attribute__((ext_vector_type(8)))  short bf16x8;
typedef __attribute__((ext_vector_type(16))) float f32x16;

union FragU { uint4 q; bf16x8 v; };

#define MFMA32 __builtin_amdgcn_mfma_f32_32x32x16_bf16

__device__ inline uint bf16rne(float x) {
    uint ub = __float_as_uint(x);
    return (ub + 0x7fffu + ((ub >> 16) & 1u)) >> 16;
}

// ======= prep_cb (coalesced): 64 blocks x 16 codes; LDS-staged, full-line writes =======
// cbt2 layout (uint4): [chit 64][k 1024]; chit = ch*4+it, it = p*2+h, d0 = ch*16+h*8.
__global__ __launch_bounds__(256)
void prep_cb(const float* __restrict__ cb, uint4* __restrict__ cbt2,
             float* __restrict__ csq, float* __restrict__ cbT,
             int* __restrict__ rcount, float* __restrict__ oloss) {
    __shared__ float Lf[16][256];   // 16 KB
    const int tid = threadIdx.x;
    const int k0 = blockIdx.x * 16;

    // ---- load 16 codebook rows, coalesced float4 ----
    #pragma unroll
    for (int pass = 0; pass < 4; ++pass) {
        int idx = pass * 1024 + tid * 4;        // float index within 16x256 tile
        int r = idx >> 8, d = idx & 255;
        float4 v = *reinterpret_cast<const float4*>(cb + (size_t)(k0 + r) * D_ + d);
        *reinterpret_cast<float4*>(&Lf[r][d]) = v;
    }
    if (blockIdx.x == 0 && tid == 0) { *rcount = 0; oloss[0] = 0.f; oloss[1] = 0.f; }
    __syncthreads();

    // ---- csq: wave w handles rows w*4..w*4+3; tree bit-identical to original ----
    {
        const int w = tid >> 6, lane = tid & 63;
        for (int rl = 0; rl < 4; ++rl) {
            int r = w * 4 + rl;
            float parts[4];
            #pragma unroll
            for (int g = 0; g < 4; ++g) {
                float s = Lf[r][g * 64 + lane];
                s = s * s;
                #pragma unroll
                for (int off = 32; off >= 1; off >>= 1) s += __shfl_xor(s, off, 64);
                parts[g] = s;
            }
            if (lane == 0)
                csq[k0 + r] = (parts[0] + parts[1]) + (parts[2] + parts[3]);
        }
    }

    // ---- cbt2: thread -> (chit, kq); 4 consecutive uint4 cells = 64 B/thread ----
    {
        const int chit = tid >> 2, kq = tid & 3;
        const int ch = chit >> 2, it = chit & 3;
        const int p = it >> 1, h = it & 1;
        const int d0 = ch * 16 + h * 8;
        #pragma unroll
        for (int kk = 0; kk < 4; ++kk) {
            int kl = kq * 4 + kk;
            uint wv[4];
            #pragma unroll
            for (int jj = 0; jj < 4; ++jj) {
                float e0 = Lf[kl][d0 + 2 * jj];
                float e1 = Lf[kl][d0 + 2 * jj + 1];
                uint h0 = bf16rne(e0), h1 = bf16rne(e1);
                if (p) {
                    h0 = bf16rne(e0 - __uint_as_float(h0 << 16));
                    h1 = bf16rne(e1 - __uint_as_float(h1 << 16));
                }
                wv[jj] = h0 | (h1 << 16);
            }
            cbt2[((size_t)chit << 10) + k0 + kl] = make_uint4(wv[0], wv[1], wv[2], wv[3]);
        }
    }

    // ---- cbT[d][k]: thread = d, writes 16 consecutive k = one full 64 B line ----
    {
        const int d = tid;
        float buf[16];
        #pragma unroll
        for (int kl = 0; kl < 16; ++kl) buf[kl] = Lf[kl][d];
        float* dst = cbT + (size_t)d * K_ + k0;
        #pragma unroll
        for (int q = 0; q < 4; ++q) {
            float4 v4 = make_float4(buf[q * 4], buf[q * 4 + 1], buf[q * 4 + 2], buf[q * 4 + 3]);
            *reinterpret_cast<float4*>(dst + q * 4) = v4;
        }
    }
}

// one K-step: 16 MFMAs against slot regs SA..SD, then refill the slot for cc+4.
#define DO_STEP(SA, SB, SC, SD, S) do {                                          \
    const int cc_ = cq * 4 + (S);                                                \
    const int ch_ = cc_ & 15;                                                    \
    FragU tf[4];                                                                 \
    _Pragma("unroll")                                                            \
    for (int j = 0; j < 4; ++j) tf[j].q = TkS[ch_ * 2 + sub][j * 32 + l31];      \
    __builtin_amdgcn_s_setprio(1);                                               \
    _Pragma("unroll")                                                            \
    for (int j = 0; j < 4; ++j)                                                  \
        acc[0][j] = MFMA32(SA.v, tf[j].v, acc[0][j], 0, 0, 0);                   \
    _Pragma("unroll")                                                            \
    for (int j = 0; j < 4; ++j)                                                  \
        acc[1][j] = MFMA32(SB.v, tf[j].v, acc[1][j], 0, 0, 0);                   \
    _Pragma("unroll")                                                            \
    for (int j = 0; j < 4; ++j)                                                  \
        acc[0][j] = MFMA32(SC.v, tf[j].v, acc[0][j], 0, 0, 0);                   \
    _Pragma("unroll")                                                            \
    for (int j = 0; j < 4; ++j)                                                  \
        acc[1][j] = MFMA32(SD.v, tf[j].v, acc[1][j], 0, 0, 0);                   \
    __builtin_amdgcn_s_setprio(0);                                               \
    if (cq < 7) {                                                                \
        const int nc_ = cc_ + 4;                                                 \
        const int noff_ = (((nc_ & 15) * 4) << 10) + ((nc_ >> 4) * 64);          \
        SA.q = cb_hi[noff_];      SB.q = cb_hi[noff_ + 32];                      \
        SC.q = cb_lo[noff_];      SD.q = cb_lo[noff_ + 32];                      \
    }                                                                            \
} while (0)

// ================= main: depth-4 prefetch K-loop + LDS-routed gather (r13/r16) ==========
__global__ __launch_bounds__(512, 1)
void vq_main(const float* __restrict__ x, const uint4* __restrict__ cbt2,
             const float* __restrict__ csqg, const float* __restrict__ cb,
             int* __restrict__ rcount, int* __restrict__ rlist,
             float* __restrict__ bdist, float* __restrict__ out,
             float* __restrict__ oidx, float* __restrict__ oloss) {
    __shared__ __align__(16) uint SMEM[17408];   // 68 KB
    uint4 (*TkS)[128] = reinterpret_cast<uint4(*)[128]>(SMEM);   // [32][128] 64 KB
    float* csqS = reinterpret_cast<float*>(SMEM + 16384);        // 4 KB

    const int tid = threadIdx.x;
    const int lane = tid & 63;
    const int sub = lane >> 5, l31 = lane & 31;
    const int w = tid >> 6;            // 0..7
    const int tok0 = blockIdx.x * 128;
    const int bb = tok0 >> 10, hw0 = tok0 & 1023;

    csqS[tid] = csqg[tid];
    csqS[tid + 512] = csqg[tid + 512];

    const uint4* cb_hi = cbt2 + (sub << 10) + w * 128 + l31;        // hi plane
    const uint4* cb_lo = cbt2 + ((2 + sub) << 10) + w * 128 + l31;  // lo plane

    // ---- depth-4 prefetch prologue: named slot registers ----
    FragU p0a, p0b, p0c, p0d, p1a, p1b, p1c, p1d,
          p2a, p2b, p2c, p2d, p3a, p3b, p3c, p3d;
    p0a.q = cb_hi[0];         p0b.q = cb_hi[32];
    p0c.q = cb_lo[0];         p0d.q = cb_lo[32];
    p1a.q = cb_hi[1 << 12];   p1b.q = cb_hi[(1 << 12) + 32];
    p1c.q = cb_lo[1 << 12];   p1d.q = cb_lo[(1 << 12) + 32];
    p2a.q = cb_hi[2 << 12];   p2b.q = cb_hi[(2 << 12) + 32];
    p2c.q = cb_lo[2 << 12];   p2d.q = cb_lo[(2 << 12) + 32];
    p3a.q = cb_hi[3 << 12];   p3b.q = cb_hi[(3 << 12) + 32];
    p3c.q = cb_lo[3 << 12];   p3d.q = cb_lo[(3 << 12) + 32];

    // ---- fused x -> bf16 staging into TkS[g][t] ----
    {
        const int t = tid & 127;
        const int dgrp = tid >> 7;     // 0..3 (wave-uniform)
        const float* xp = x + (size_t)bb * DHW + hw0 + t;
        #pragma unroll
        for (int i = 0; i < 8; ++i) {
            int g = i * 4 + dgrp;      // 0..31, d = 8g..8g+7
            float v[8];
            #pragma unroll
            for (int e = 0; e < 8; ++e)
                v[e] = xp[(size_t)(g * 8 + e) * HW_];
            uint wd[4];
            #pragma unroll
            for (int jj = 0; jj < 4; ++jj)
                wd[jj] = bf16rne(v[2 * jj]) | (bf16rne(v[2 * jj + 1]) << 16);
            TkS[g][t] = make_uint4(wd[0], wd[1], wd[2], wd[3]);
        }
    }
    __syncthreads();

    f32x16 acc[2][4] = {};
    float v1[4], v2[4]; int k1[4];
    #pragma unroll
    for (int j = 0; j < 4; ++j) { v1[j] = 3.4e38f; v2[j] = 3.4e38f; k1[j] = 0; }

    for (int cq = 0; cq < 8; ++cq) {
        DO_STEP(p0a, p0b, p0c, p0d, 0);
        DO_STEP(p1a, p1b, p1c, p1d, 1);
        DO_STEP(p2a, p2b, p2c, p2d, 2);
        DO_STEP(p3a, p3b, p3c, p3d, 3);

        if ((cq & 3) == 3) {
            const int ct = cq >> 2;
            const int cbase = w * 128 + ct * 64 + sub * 4;
            #pragma unroll
            for (int f = 0; f < 2; ++f) {
                #pragma unroll
                for (int g8 = 0; g8 < 4; ++g8) {
                    float4 cs4 = *reinterpret_cast<const float4*>(&csqS[cbase + f * 32 + g8 * 8]);
                    const float csa[4] = {cs4.x, cs4.y, cs4.z, cs4.w};
                    #pragma unroll
                    for (int q = 0; q < 4; ++q) {
                        int code = cbase + f * 32 + g8 * 8 + q;
                        int r = g8 * 4 + q;
                        #pragma unroll
                        for (int j = 0; j < 4; ++j) {
                            float s = fmaf(-2.f, acc[f][j][r], csa[q]);
                            bool c = s < v1[j];
                            v2[j] = c ? v1[j] : fminf(v2[j], s);
                            k1[j] = c ? code : k1[j];
                            v1[j] = c ? s : v1[j];
                        }
                    }
                }
            }
            const f32x16 zf = {};
            #pragma unroll
            for (int f = 0; f < 2; ++f)
                #pragma unroll
                for (int j = 0; j < 4; ++j) acc[f][j] = zf;
        }
    }

    // ---- merge sub halves ----
    #pragma unroll
    for (int j = 0; j < 4; ++j) {
        float ov1 = __shfl_xor(v1[j], 32, 64);
        float ov2 = __shfl_xor(v2[j], 32, 64);
        int   ok1 = __shfl_xor(k1[j], 32, 64);
        float nv2 = fminf(fminf(v2[j], ov2), fmaxf(v1[j], ov1));
        if (ov1 < v1[j] || (ov1 == v1[j] && ok1 < k1[j])) { v1[j] = ov1; k1[j] = ok1; }
        v2[j] = nv2;
    }
    __syncthreads();
    float* red = reinterpret_cast<float*>(SMEM);            // [8 w][128 t][3]
    int* bestk_s = reinterpret_cast<int*>(SMEM + 17280);    // 128 ints (tail, survives S2)
    if (sub == 0) {
        #pragma unroll
        for (int j = 0; j < 4; ++j) {
            int t = j * 32 + l31;
            red[(w * 128 + t) * 3 + 0] = v1[j];
            red[(w * 128 + t) * 3 + 1] = v2[j];
            red[(w * 128 + t) * 3 + 2] = __int_as_float(k1[j]);
        }
    }
    __syncthreads();
    if (tid < 128) {
        float bv1 = red[tid * 3], bv2 = red[tid * 3 + 1];
        int bk = __float_as_int(red[tid * 3 + 2]);
        #pragma unroll
        for (int m = 1; m < 8; ++m) {
            float a1 = red[(m * 128 + tid) * 3], a2 = red[(m * 128 + tid) * 3 + 1];
            int ak = __float_as_int(red[(m * 128 + tid) * 3 + 2]);
            float nv2 = fminf(fminf(bv2, a2), fmaxf(bv1, a1));
            if (a1 < bv1 || (a1 == bv1 && ak < bk)) { bv1 = a1; bk = ak; }
            bv2 = nv2;
        }
        int n = tok0 + tid;
        bestk_s[tid] = bk;
        bdist[n] = bv1;
        oidx[n] = (float)bk;
        if (bv2 - bv1 < MARGIN) rlist[atomicAdd(rcount, 1)] = n;
        float v = bv1;
        #pragma unroll
        for (int off = 32; off >= 1; off >>= 1) v += __shfl_xor(v, off, 64);
        if ((tid & 63) == 0) {
            float t2 = v * (1.0f / 8388608.0f);
            atomicAdd(&oloss[0], t2);
            atomicAdd(&oloss[1], t2);
        }
    }
    __syncthreads();

    // ---- gather via LDS transpose: 2 halves of 64 tokens ----
    float* S2 = reinterpret_cast<float*>(SMEM);   // [64][260] = 66,560 B
    #pragma unroll 1
    for (int h = 0; h < 2; ++h) {
        #pragma unroll
        for (int i = 0; i < 8; ++i) {
            int r = w * 8 + i;                       // 0..63
            int kk = bestk_s[h * 64 + r];
            float4 cw4 = *reinterpret_cast<const float4*>(cb + (size_t)kk * D_ + lane * 4);
            *reinterpret_cast<float4*>(&S2[r * 260 + lane * 4]) = cw4;
        }
        __syncthreads();
        {
            const int q = tid & 15, dg = tid >> 4;   // 16 x 32
            const size_t obase = (size_t)bb * DHW + hw0 + h * 64 + q * 4;
            #pragma unroll
            for (int dd = 0; dd < 8; ++dd) {
                int d = dg * 8 + dd;
                float4 wv;
                wv.x = S2[(q * 4 + 0) * 260 + d];
                wv.y = S2[(q * 4 + 1) * 260 + d];
                wv.z = S2[(q * 4 + 2) * 260 + d];
                wv.w = S2[(q * 4 + 3) * 260 + d];
                *reinterpret_cast<float4*>(out + obase + (size_t)d * HW_) = wv;
            }
        }
        __syncthreads();
    }
}

// ===== exact fp32 refine: 256 thr, batch-8, 4 codes/thread (FMA:LDS = 4:1) + fix-up =====
__global__ __launch_bounds__(256)
void vq_refine(const float* __restrict__ x, const float* __restrict__ cb,
               const float* __restrict__ cbT, const float* __restrict__ csq,
               const int* __restrict__ rcount, const int* __restrict__ rlist,
               const float* __restrict__ bdist, float* __restrict__ out,
               float* __restrict__ oidx, float* __restrict__ oloss) {
    __shared__ float xv[8][256];
    __shared__ float xsq[8];
    __shared__ float wredv[4][8];
    __shared__ int   wredk[4][8];
    __shared__ int   kfin[8];
    const int tid = threadIdx.x;
    const int cnt = min(rcount[0], N_);
    for (int base = blockIdx.x * 8; base < cnt; base += gridDim.x * 8) {
        const int m = min(8, cnt - base);
        __syncthreads();
        for (int j = 0; j < m; ++j) {
            int n = rlist[base + j];
            int b = n >> 10, hw = n & 1023;
            xv[j][tid] = x[(size_t)b * DHW + (size_t)tid * HW_ + hw];
        }
        for (int j = m; j < 8; ++j) xv[j][tid] = 0.f;
        __syncthreads();
        {   // xsq: 8 groups of 32 lanes (identical tree to all prior passing rounds)
            int g = tid >> 5, l = tid & 31;
            float s = 0.f;
            #pragma unroll
            for (int d8 = 0; d8 < 8; ++d8) { float v = xv[g][d8 * 32 + l]; s = fmaf(v, v, s); }
            #pragma unroll
            for (int mm = 1; mm < 32; mm <<= 1) s += __shfl_xor(s, mm, 64);
            if (l == 0) xsq[g] = s;
        }
        __syncthreads();

        float dots[4][8];
        #pragma unroll
        for (int c4 = 0; c4 < 4; ++c4)
            #pragma unroll
            for (int j = 0; j < 8; ++j) dots[c4][j] = 0.f;

        const float* cbase = cbT + tid;
        for (int d0 = 0; d0 < 256; d0 += 8) {
            float xr[8][8];
            #pragma unroll
            for (int j = 0; j < 8; ++j) {
                float4 a = *reinterpret_cast<const float4*>(&xv[j][d0]);
                float4 b = *reinterpret_cast<const float4*>(&xv[j][d0 + 4]);
                xr[j][0] = a.x; xr[j][1] = a.y; xr[j][2] = a.z; xr[j][3] = a.w;
                xr[j][4] = b.x; xr[j][5] = b.y; xr[j][6] = b.z; xr[j][7] = b.w;
            }
            #pragma unroll
            for (int c4 = 0; c4 < 4; ++c4) {
                float cv[8];
                #pragma unroll
                for (int u = 0; u < 8; ++u)
                    cv[u] = cbase[(size_t)(d0 + u) * K_ + c4 * 256];   // coalesced
                #pragma unroll
                for (int u = 0; u < 8; ++u)
                    #pragma unroll
                    for (int j = 0; j < 8; ++j)
                        dots[c4][j] = fmaf(cv[u], xr[j][u], dots[c4][j]);
            }
        }

        float bv[8]; int bk[8];
        #pragma unroll
        for (int j = 0; j < 8; ++j) { bv[j] = 3.4e38f; bk[j] = 0; }
        #pragma unroll
        for (int c4 = 0; c4 < 4; ++c4) {
            const int code = c4 * 256 + tid;
            const float cs = csq[code];
            #pragma unroll
            for (int j = 0; j < 8; ++j) {
                float dist = fmaf(-2.f, dots[c4][j], xsq[j]) + cs;
                if (dist < bv[j]) { bv[j] = dist; bk[j] = code; }
            }
        }
        #pragma unroll
        for (int j = 0; j < 8; ++j) {
            if (j < m) {
                float v = bv[j]; int k = bk[j];
                #pragma unroll
                for (int mm = 1; mm < 64; mm <<= 1) {
                    float ov = __shfl_xor(v, mm, 64);
                    int   ok = __shfl_xor(k, mm, 64);
                    if (ov < v || (ov == v && ok < k)) { v = ov; k = ok; }
                }
                if ((tid & 63) == 0) { wredv[tid >> 6][j] = v; wredk[tid >> 6][j] = k; }
            }
        }
        __syncthreads();
        if (tid < m) {
            float v = wredv[0][tid]; int k = wredk[0][tid];
            #pragma unroll
            for (int q = 1; q < 4; ++q) {
                if (wredv[q][tid] < v || (wredv[q][tid] == v && wredk[q][tid] < k)) {
                    v = wredv[q][tid]; k = wredk[q][tid];
                }
            }
            int n = rlist[base + tid];
            kfin[tid] = k;
            oidx[n] = (float)k;
            float delta = (v - bdist[n]) * (1.0f / 8388608.0f);
            atomicAdd(&oloss[0], delta);
            atomicAdd(&oloss[1], delta);
        }
        __syncthreads();
        for (int j = 0; j < m; ++j) {
            int n = rlist[base + j];
            int b = n >> 10, hw = n & 1023;
            out[(size_t)b * DHW + (size_t)tid * HW_ + hw] = cb[(size_t)kfin[j] * D_ + tid];
        }
        __syncthreads();
    }
}

extern "C" void kernel_launch(void* const* d_in, const int* in_sizes, int n_in,
                              void* d_out, int out_size, void* d_ws, size_t ws_size,
                              hipStream_t stream) {
    const float* x  = (const float*)d_in[0];
    const float* cb = (const float*)d_in[1];

    float* out   = (float*)d_out;            // 8388608 floats
    float* oidx  = out + 8388608;            // 32768 floats
    float* oloss = out + 8388608 + 32768;    // 2 floats

    uint* wsb = (uint*)d_ws;
    uint4*  cbt2  = (uint4*)wsb;             // 1 MB
    float*  csq   = (float*)(wsb + 262144);  // 1024
    float*  cbT   = (float*)(wsb + 263168);  // 1 MB, fp32 [d][k]
    int*    rcount= (int*)  (wsb + 525312);  // 1
    int*    rlist = (int*)  (wsb + 525316);  // 32768
    float*  bdist = (float*)(wsb + 558084);  // 32768

    prep_cb <<<64, 256, 0, stream>>>(cb, cbt2, csq, cbT, rcount, oloss);
    vq_main <<<256, 512, 0, stream>>>(x, cbt2, csq, cb, rcount, rlist, bdist, out, oidx, oloss);
    vq_refine<<<512, 256, 0, stream>>>(x, cb, cbT, csq, rcount, rlist, bdist, out, oidx, oloss);
}